// Round 20
// baseline (532.674 us; speedup 1.0000x reference)
//
#include <hip/hip_runtime.h>
#include <hip/hip_bf16.h>
#include <math.h>

#define N_NODES 20000
#define N_EDGES 320000
#define IN_DIM 128
#define HID 256
#define HEADS 8
#define DH 32
#define LAYERS 3
#define NUM_GRAPHS 64
#define OUT_DIM 10
#define SLOPE 0.2f

// src-bucketed CSR: bucket = src >> 12 (4096 nodes = 2 MB of fsb per bucket)
#define NBKT 5
#define N_BINS (N_NODES * NBKT)

typedef __bf16 bf16x8 __attribute__((ext_vector_type(8)));
typedef float f32x4 __attribute__((ext_vector_type(4)));

static __device__ __forceinline__ unsigned short f2bfbits(float v) {
    __bf16 b = (__bf16)v;
    return __builtin_bit_cast(unsigned short, b);
}
// unpack 8 bf16 (in a uint4) -> 8 fp32, exact
static __device__ __forceinline__ void unpack8(uint4 u, float* f) {
    unsigned p0 = u.x, p1 = u.y, p2 = u.z, p3 = u.w;
    f[0] = __builtin_bit_cast(float, p0 << 16);
    f[1] = __builtin_bit_cast(float, p0 & 0xffff0000u);
    f[2] = __builtin_bit_cast(float, p1 << 16);
    f[3] = __builtin_bit_cast(float, p1 & 0xffff0000u);
    f[4] = __builtin_bit_cast(float, p2 << 16);
    f[5] = __builtin_bit_cast(float, p2 & 0xffff0000u);
    f[6] = __builtin_bit_cast(float, p3 << 16);
    f[7] = __builtin_bit_cast(float, p3 & 0xffff0000u);
}
// unpack 4 bf16 (in a uint2) -> 4 fp32, exact
static __device__ __forceinline__ void unpack4(uint2 u, float* f) {
    f[0] = __builtin_bit_cast(float, u.x << 16);
    f[1] = __builtin_bit_cast(float, u.x & 0xffff0000u);
    f[2] = __builtin_bit_cast(float, u.y << 16);
    f[3] = __builtin_bit_cast(float, u.y & 0xffff0000u);
}

// async 16B global->LDS (DMA, wave-uniform LDS base + lane*16)
typedef const __attribute__((address_space(1))) unsigned int* as1_u32p;
typedef __attribute__((address_space(3))) unsigned int* as3_u32p;
static __device__ __forceinline__ void async_cp16(const unsigned short* g, unsigned short* l) {
    __builtin_amdgcn_global_load_lds((as1_u32p)g, (as3_u32p)l, 16, 0, 0);
}

// ---------------- fused prep: zero cnt+hg, feature cast, weight transpose/cast ----------------
#define CAST_N4 (N_NODES * IN_DIM / 4)
#define WTRANS_TOTAL (IN_DIM * HID + 6 * HID * HID)
#define ZERO_TOTAL (N_BINS + NUM_GRAPHS * HID)
#define PREP_TOTAL (CAST_N4 + WTRANS_TOTAL + ZERO_TOTAL)
__global__ void prep_kernel(const float* __restrict__ feat,
                            const float* __restrict__ Win,
                            const float* __restrict__ Wsrc,
                            const float* __restrict__ Wdst,
                            unsigned short* __restrict__ featH,
                            unsigned short* __restrict__ WinT,
                            unsigned short* __restrict__ WT,
                            int* __restrict__ cnt, float* __restrict__ hg) {
    int idx = blockIdx.x * blockDim.x + threadIdx.x;
    if (idx < CAST_N4) {
        float4 v = ((const float4*)feat)[idx];
        ushort4 o;
        o.x = f2bfbits(v.x); o.y = f2bfbits(v.y);
        o.z = f2bfbits(v.z); o.w = f2bfbits(v.w);
        ((ushort4*)featH)[idx] = o;
    } else if (idx < CAST_N4 + WTRANS_TOTAL) {
        int j = idx - CAST_N4;
        if (j < IN_DIM * HID) {
            int n = j / IN_DIM, k = j % IN_DIM;
            WinT[j] = f2bfbits(Win[k * HID + n]);
        } else {
            int r6 = j - IN_DIM * HID;
            int mat = r6 >> 16;
            int r = r6 & 65535;
            int n = r >> 8, k = r & 255;
            const float* base = (mat < 3) ? (Wsrc + (size_t)mat * 65536)
                                          : (Wdst + (size_t)(mat - 3) * 65536);
            WT[r6] = f2bfbits(base[k * 256 + n]);
        }
    } else if (idx < PREP_TOTAL) {
        int z = idx - CAST_N4 - WTRANS_TOTAL;
        if (z < N_BINS) cnt[z] = 0;
        else hg[z - N_BINS] = 0.f;
    }
}

// ---------------- CSR build, keyed by (dst, src-bucket) ----------------
__global__ void count_kernel(const int* __restrict__ src, const int* __restrict__ dst,
                             int* __restrict__ cnt) {
    int e = blockIdx.x * blockDim.x + threadIdx.x;
    if (e < N_EDGES) atomicAdd(&cnt[dst[e] * NBKT + (src[e] >> 12)], 1);
}

// parallel single-block scan over N_BINS bins: 1024 threads, two-pass cnt read
#define SCAN_CHUNK ((N_BINS + 1023) / 1024)   // 98
__global__ __launch_bounds__(1024) void scan_kernel(const int* __restrict__ cnt,
                                                    int* __restrict__ offs,
                                                    int* __restrict__ cursor) {
    __shared__ int wsum[16];
    int t = threadIdx.x;
    int beg = t * SCAN_CHUNK;
    int end = beg + SCAN_CHUNK; if (end > N_BINS) end = N_BINS;

    int s = 0;
    for (int i = beg; i < end; ++i) s += cnt[i];

    int v = s;
#pragma unroll
    for (int d = 1; d < 64; d <<= 1) {
        int u = __shfl_up(v, d, 64);
        if ((t & 63) >= d) v += u;
    }
    if ((t & 63) == 63) wsum[t >> 6] = v;
    __syncthreads();
    if (t < 16) {
        int wv = wsum[t];
#pragma unroll
        for (int d = 1; d < 16; d <<= 1) {
            int u = __shfl_up(wv, d, 64);
            if (t >= d) wv += u;
        }
        wsum[t] = wv;
    }
    __syncthreads();
    int waveoff = (t >> 6) ? wsum[(t >> 6) - 1] : 0;
    int run = waveoff + v - s;
    for (int i = beg; i < end; ++i) {
        offs[i] = run; cursor[i] = run;
        run += cnt[i];
    }
    if (t == 0) offs[N_BINS] = wsum[15];
}

__global__ void fill_kernel(const int* __restrict__ src, const int* __restrict__ dst,
                            int* __restrict__ cursor, int* __restrict__ csr_src) {
    int e = blockIdx.x * blockDim.x + threadIdx.x;
    if (e < N_EDGES) {
        int sv = src[e];
        int p = atomicAdd(&cursor[dst[e] * NBKT + (sv >> 12)], 1);
        csr_src[p] = sv;
    }
}

// ---------------- MFMA GEMM (round-17 structure): bf16 A, M64 x N128, BK=32 ----------------
template <int DUAL>
__global__ __launch_bounds__(256, 4) void mfma_gemm(
    const unsigned short* __restrict__ Ah,
    const unsigned short* __restrict__ BT1, const float* __restrict__ bias1,
    unsigned short* __restrict__ O1,
    const unsigned short* __restrict__ BT2, const float* __restrict__ bias2,
    unsigned short* __restrict__ O2,
    int M, int K, int N) {
    __shared__ __align__(16) unsigned short As[2][64 * 32];
    __shared__ __align__(16) unsigned short Bs1[2][128 * 32];
    __shared__ __align__(16) unsigned short Bs2[DUAL ? 2 : 1][DUAL ? 128 * 32 : 8];

    const int t = threadIdx.x;
    const int wv = t >> 6, lane = t & 63, quad = lane >> 4, l15 = lane & 15;
    const int m0 = blockIdx.x * 64, n0 = blockIdx.y * 128;

    const int sA = wv * 64 + lane;
    const int rA = sA >> 2, cA = (sA & 3) ^ ((rA >> 1) & 3);
    int gmA = m0 + rA; if (gmA >= M) gmA = M - 1;
    const size_t offA = (size_t)gmA * K + cA * 8;
    const int sB0 = wv * 64 + lane, sB1v = sB0 + 256;
    const int rB0 = sB0 >> 2, cB0 = (sB0 & 3) ^ ((rB0 >> 1) & 3);
    const int rB1 = sB1v >> 2, cB1 = (sB1v & 3) ^ ((rB1 >> 1) & 3);
    const size_t offB0 = (size_t)(n0 + rB0) * K + cB0 * 8;
    const size_t offB1 = (size_t)(n0 + rB1) * K + cB1 * 8;

    auto issue = [&](int buf, int k0) {
        async_cp16(Ah + offA + k0, &As[buf][wv * 512]);
        async_cp16(BT1 + offB0 + k0, &Bs1[buf][wv * 512]);
        async_cp16(BT1 + offB1 + k0, &Bs1[buf][2048 + wv * 512]);
        if (DUAL) {
            async_cp16(BT2 + offB0 + k0, &Bs2[buf][wv * 512]);
            async_cp16(BT2 + offB1 + k0, &Bs2[buf][2048 + wv * 512]);
        }
    };

    const int mrow0 = (wv >> 1) * 32;
    const int ncb = (wv & 1) * 64;

    f32x4 zero = {0.f, 0.f, 0.f, 0.f};
    f32x4 acc1[2][4], acc2[2][4];
#pragma unroll
    for (int mi = 0; mi < 2; ++mi)
#pragma unroll
        for (int t4 = 0; t4 < 4; ++t4) { acc1[mi][t4] = zero; acc2[mi][t4] = zero; }

    issue(0, 0);
    int buf = 0;
    for (int k0 = 0; k0 < K; k0 += 32, buf ^= 1) {
        __syncthreads();
        if (k0 + 32 < K) issue(buf ^ 1, k0 + 32);

        bf16x8 aF[2];
#pragma unroll
        for (int mi = 0; mi < 2; ++mi) {
            int row = mrow0 + mi * 16 + l15;
            int aoff = row * 32 + ((quad ^ ((row >> 1) & 3)) << 3);
            aF[mi] = __builtin_bit_cast(bf16x8, *(const uint4*)(&As[buf][0] + aoff));
        }
#pragma unroll
        for (int t4 = 0; t4 < 4; ++t4) {
            int brow = ncb + t4 * 16 + l15;
            int boff = brow * 32 + ((quad ^ ((brow >> 1) & 3)) << 3);
            bf16x8 b1 = __builtin_bit_cast(bf16x8, *(const uint4*)(&Bs1[buf][0] + boff));
#pragma unroll
            for (int mi = 0; mi < 2; ++mi)
                acc1[mi][t4] = __builtin_amdgcn_mfma_f32_16x16x32_bf16(aF[mi], b1, acc1[mi][t4], 0, 0, 0);
            if (DUAL) {
                bf16x8 b2 = __builtin_bit_cast(bf16x8, *(const uint4*)(&Bs2[buf][0] + boff));
#pragma unroll
                for (int mi = 0; mi < 2; ++mi)
                    acc2[mi][t4] = __builtin_amdgcn_mfma_f32_16x16x32_bf16(aF[mi], b2, acc2[mi][t4], 0, 0, 0);
            }
        }
    }

    float bia1[4], bia2[4];
#pragma unroll
    for (int t4 = 0; t4 < 4; ++t4) {
        bia1[t4] = bias1[n0 + ncb + t4 * 16 + l15];
        bia2[t4] = DUAL ? bias2[n0 + ncb + t4 * 16 + l15] : 0.f;
    }
#pragma unroll
    for (int mi = 0; mi < 2; ++mi) {
#pragma unroll
        for (int t4 = 0; t4 < 4; ++t4) {
            int gn = n0 + ncb + t4 * 16 + l15;
#pragma unroll
            for (int r = 0; r < 4; ++r) {
                int gm = m0 + mrow0 + mi * 16 + quad * 4 + r;
                if (gm < M) {
                    float v = acc1[mi][t4][r] + bia1[t4];
                    O1[(size_t)gm * N + gn] = f2bfbits(v);
                    if (DUAL) {
                        float v2 = acc2[mi][t4][r] + bia2[t4];
                        O2[(size_t)gm * N + gn] = f2bfbits(v2);
                    }
                }
            }
        }
    }
}

// ---------------- GATv2 aggregation v4, bf16-unified h, bucket-sorted edges ----------------
// Half-wave (32 lanes) per node; block = 8 nodes; no-max softmax (commutative ->
// bucket-reordered edges are exact-equivalent up to fp reassociation).
// Node's edges are the contiguous range [offs[5n], offs[5n+5]), sorted by src
// bucket, so concurrently-running blocks read the same ~2MB fsb region.
__global__ __launch_bounds__(256) void gat_agg2(
    const unsigned short* __restrict__ fsb, const unsigned short* __restrict__ fdb,
    unsigned short* __restrict__ hb, const int* __restrict__ offs,
    const int* __restrict__ csr_src, const float* __restrict__ attn_l) {
    int tid = threadIdx.x;
    int node = (blockIdx.x * blockDim.x + tid) >> 5;
    if (node >= N_NODES) return;
    int l32 = tid & 31;
    int dbase = l32 * 8;
    int abase = (l32 >> 2) * DH + (l32 & 3) * 8;

    float a[8];
#pragma unroll
    for (int j = 0; j < 8; ++j) a[j] = attn_l[abase + j];

    float fdv[8];
    unpack8(*(const uint4*)(fdb + (size_t)node * HID + dbase), fdv);

    float ssum0 = 0.f, ssum1 = 0.f;
    float acc0[8], acc1[8];
#pragma unroll
    for (int j = 0; j < 8; ++j) { acc0[j] = 0.f; acc1[j] = 0.f; }

    auto procE = [&](uint4 u, float* acc, float& ssum) {
        float fsv[8];
        unpack8(u, fsv);
        float p = 0.f;
#pragma unroll
        for (int j = 0; j < 8; ++j) {
            float e = fsv[j] + fdv[j];
            e = fmaxf(e, SLOPE * e);   // leakyrelu (slope<1)
            p += e * a[j];
        }
        p += __shfl_xor(p, 1, 64);
        p += __shfl_xor(p, 2, 64);
        float w = __expf(p);
        ssum += w;
#pragma unroll
        for (int j = 0; j < 8; ++j) acc[j] += w * fsv[j];
    };

    const unsigned short* fsl = fsb + dbase;
    int beg = offs[node * NBKT], end = offs[node * NBKT + NBKT];
    int nfull = (end - beg) >> 2;
    const int limit = beg + nfull * 4;

    uint4 cu0, cu1, cu2, cu3;
    int ci0, ci1, ci2, ci3;
    int base = beg + 8;
    bool have = (nfull >= 1);
    bool haveN = (nfull >= 2);
    if (have) {
        int s0 = csr_src[beg], s1 = csr_src[beg + 1];
        int s2 = csr_src[beg + 2], s3 = csr_src[beg + 3];
        if (haveN) {
            ci0 = csr_src[beg + 4]; ci1 = csr_src[beg + 5];
            ci2 = csr_src[beg + 6]; ci3 = csr_src[beg + 7];
        }
        cu0 = *(const uint4*)(fsl + (size_t)s0 * HID);
        cu1 = *(const uint4*)(fsl + (size_t)s1 * HID);
        cu2 = *(const uint4*)(fsl + (size_t)s2 * HID);
        cu3 = *(const uint4*)(fsl + (size_t)s3 * HID);
    }
    while (have) {
        uint4 nu0, nu1, nu2, nu3;
        int ni0, ni1, ni2, ni3;
        if (haveN) {
            nu0 = *(const uint4*)(fsl + (size_t)ci0 * HID);
            nu1 = *(const uint4*)(fsl + (size_t)ci1 * HID);
            nu2 = *(const uint4*)(fsl + (size_t)ci2 * HID);
            nu3 = *(const uint4*)(fsl + (size_t)ci3 * HID);
        }
        bool haveNN = (base + 4 <= limit);
        if (haveNN) {
            ni0 = csr_src[base]; ni1 = csr_src[base + 1];
            ni2 = csr_src[base + 2]; ni3 = csr_src[base + 3];
        }
        base += 4;
        procE(cu0, acc0, ssum0);
        procE(cu1, acc1, ssum1);
        procE(cu2, acc0, ssum0);
        procE(cu3, acc1, ssum1);
        if (haveN) { cu0 = nu0; cu1 = nu1; cu2 = nu2; cu3 = nu3; }
        if (haveNN) { ci0 = ni0; ci1 = ni1; ci2 = ni2; ci3 = ni3; }
        have = haveN; haveN = haveNN;
    }
    for (int idx = limit; idx < end; ++idx) {
        int sv = csr_src[idx];
        procE(*(const uint4*)(fsl + (size_t)sv * HID), acc0, ssum0);
    }

    float ssum = ssum0 + ssum1;
    float acc[8];
#pragma unroll
    for (int j = 0; j < 8; ++j) acc[j] = acc0[j] + acc1[j];

    float inv = ssum > 0.f ? 1.f / ssum : 0.f;
    float hv[8];
    unpack8(*(const uint4*)(hb + (size_t)node * HID + dbase), hv);
    unsigned short ob[8];
#pragma unroll
    for (int j = 0; j < 8; ++j) {
        float o = fmaxf(acc[j] * inv + hv[j], 0.f);
        ob[j] = f2bfbits(o);
    }
    *(uint4*)(hb + (size_t)node * HID + dbase) = *(uint4*)ob;
}

// ---------------- graph sum-pool (bf16 h; graph_ids sorted) ----------------
#define POOL_CHUNK 32
__global__ __launch_bounds__(64) void pool_kernel(const unsigned short* __restrict__ hb,
                                                  const int* __restrict__ gid,
                                                  float* __restrict__ hg) {
    int t = threadIdx.x;
    int n0 = blockIdx.x * POOL_CHUNK;
    int n1 = n0 + POOL_CHUNK; if (n1 > N_NODES) n1 = N_NODES;
    if (n0 >= N_NODES) return;
    float acc[4] = {0.f, 0.f, 0.f, 0.f};
    int cur = gid[n0];
    for (int n = n0; n < n1; ++n) {
        int g = gid[n];
        if (g != cur) {
            atomicAdd(&hg[(size_t)cur * HID + t * 4 + 0], acc[0]);
            atomicAdd(&hg[(size_t)cur * HID + t * 4 + 1], acc[1]);
            atomicAdd(&hg[(size_t)cur * HID + t * 4 + 2], acc[2]);
            atomicAdd(&hg[(size_t)cur * HID + t * 4 + 3], acc[3]);
            acc[0] = acc[1] = acc[2] = acc[3] = 0.f;
            cur = g;
        }
        float v[4];
        unpack4(*(const uint2*)(hb + (size_t)n * HID + t * 4), v);
        acc[0] += v[0]; acc[1] += v[1]; acc[2] += v[2]; acc[3] += v[3];
    }
    atomicAdd(&hg[(size_t)cur * HID + t * 4 + 0], acc[0]);
    atomicAdd(&hg[(size_t)cur * HID + t * 4 + 1], acc[1]);
    atomicAdd(&hg[(size_t)cur * HID + t * 4 + 2], acc[2]);
    atomicAdd(&hg[(size_t)cur * HID + t * 4 + 3], acc[3]);
}

// ---------------- classifier: one block per graph ----------------
__global__ __launch_bounds__(256) void classifier_kernel(
    const float* __restrict__ hg,
    const float* __restrict__ Wc1, const float* __restrict__ bc1,
    const float* __restrict__ Wc2, const float* __restrict__ bc2,
    const float* __restrict__ Wc3, const float* __restrict__ bc3,
    float* __restrict__ out) {
    __shared__ float xin[HID];
    __shared__ float x1[HID];
    __shared__ float x2[HID / 2];
    int g = blockIdx.x, t = threadIdx.x;
    xin[t] = hg[(size_t)g * HID + t];
    __syncthreads();
    {
        float acc = bc1[t];
        for (int k = 0; k < HID; ++k) acc += xin[k] * Wc1[k * HID + t];
        x1[t] = fmaxf(acc, 0.f);
    }
    __syncthreads();
    if (t < HID / 2) {
        float acc = bc2[t];
        for (int k = 0; k < HID; ++k) acc += x1[k] * Wc2[k * (HID / 2) + t];
        x2[t] = fmaxf(acc, 0.f);
    }
    __syncthreads();
    if (t < OUT_DIM) {
        float acc = bc3[t];
        for (int k = 0; k < HID / 2; ++k) acc += x2[k] * Wc3[k * OUT_DIM + t];
        out[g * OUT_DIM + t] = acc;
    }
}

// ---------------- launch ----------------
extern "C" void kernel_launch(void* const* d_in, const int* in_sizes, int n_in,
                              void* d_out, int out_size, void* d_ws, size_t ws_size,
                              hipStream_t stream) {
    const float* feature = (const float*)d_in[0];
    const float* W_in   = (const float*)d_in[1];
    const float* b_in   = (const float*)d_in[2];
    const float* W_src  = (const float*)d_in[3];
    const float* b_src  = (const float*)d_in[4];
    const float* W_dst  = (const float*)d_in[5];
    const float* b_dst  = (const float*)d_in[6];
    const float* attn   = (const float*)d_in[7];
    const float* Wc1    = (const float*)d_in[8];
    const float* bc1    = (const float*)d_in[9];
    const float* Wc2    = (const float*)d_in[10];
    const float* bc2    = (const float*)d_in[11];
    const float* Wc3    = (const float*)d_in[12];
    const float* bc3    = (const float*)d_in[13];
    const int* src     = (const int*)d_in[14];
    const int* dst     = (const int*)d_in[15];
    const int* gid     = (const int*)d_in[16];
    float* out = (float*)d_out;

    char* w = (char*)d_ws;
    auto alloc = [&](size_t bytes) -> void* {
        void* p = (void*)w;
        w += (bytes + 255) & ~(size_t)255;
        return p;
    };
    unsigned short* hb  = (unsigned short*)alloc((size_t)N_NODES * HID * 2);  // unified bf16 h
    unsigned short* fsb = (unsigned short*)alloc((size_t)N_NODES * HID * 2);
    unsigned short* fdb = (unsigned short*)alloc((size_t)N_NODES * HID * 2);
    float* hg    = (float*)alloc((size_t)NUM_GRAPHS * HID * 4);
    int* cnt     = (int*)alloc((size_t)N_BINS * 4);
    int* offs    = (int*)alloc((size_t)(N_BINS + 1) * 4);
    int* cursor  = (int*)alloc((size_t)N_BINS * 4);
    int* csr_src = (int*)alloc((size_t)N_EDGES * 4);
    unsigned short* WinT = (unsigned short*)alloc((size_t)IN_DIM * HID * 2);
    unsigned short* WT   = (unsigned short*)alloc((size_t)6 * HID * HID * 2);
    unsigned short* featH = (unsigned short*)alloc((size_t)N_NODES * IN_DIM * 2);
    (void)alloc(4096);  // slack for clamped staging overreach

    // prep: zero cnt+hg, feature cast, weight transposes (one dispatch)
    hipLaunchKernelGGL(prep_kernel, dim3((PREP_TOTAL + 255) / 256), dim3(256), 0, stream,
                       feature, W_in, W_src, W_dst, featH, WinT, WT, cnt, hg);

    // CSR build keyed by (dst, src-bucket)
    hipLaunchKernelGGL(count_kernel, dim3((N_EDGES + 255) / 256), dim3(256), 0, stream,
                       src, dst, cnt);
    hipLaunchKernelGGL(scan_kernel, dim3(1), dim3(1024), 0, stream, cnt, offs, cursor);
    hipLaunchKernelGGL(fill_kernel, dim3((N_EDGES + 255) / 256), dim3(256), 0, stream,
                       src, dst, cursor, csr_src);

    dim3 ggrid((N_NODES + 63) / 64, HID / 128);  // 313 x 2

    // input projection: hb = bf16(feature @ W_in + b_in)
    hipLaunchKernelGGL((mfma_gemm<0>), ggrid, dim3(256), 0, stream,
                       featH, WinT, b_in, hb,
                       (const unsigned short*)nullptr, (const float*)nullptr,
                       (unsigned short*)nullptr,
                       N_NODES, IN_DIM, HID);

    // GATv2 layers
    for (int l = 0; l < LAYERS; ++l) {
        hipLaunchKernelGGL((mfma_gemm<1>), ggrid, dim3(256), 0, stream,
                           hb,
                           WT + (size_t)l * HID * HID, b_src + (size_t)l * HID, fsb,
                           WT + (size_t)(3 + l) * HID * HID, b_dst + (size_t)l * HID, fdb,
                           N_NODES, HID, HID);
        hipLaunchKernelGGL(gat_agg2, dim3(N_NODES / 8), dim3(256), 0, stream,
                           fsb, fdb, hb, offs, csr_src, attn + (size_t)l * HEADS * DH);
    }

    // pool + classifier
    hipLaunchKernelGGL(pool_kernel, dim3((N_NODES + POOL_CHUNK - 1) / POOL_CHUNK), dim3(64), 0, stream,
                       hb, gid, hg);
    hipLaunchKernelGGL(classifier_kernel, dim3(NUM_GRAPHS), dim3(256), 0, stream,
                       hg, Wc1, bc1, Wc2, bc2, Wc3, bc3, out);
}

// Round 21
// 312.504 us; speedup vs baseline: 1.7045x; 1.7045x over previous
//
#include <hip/hip_runtime.h>
#include <hip/hip_bf16.h>
#include <math.h>

#define N_NODES 20000
#define N_EDGES 320000
#define IN_DIM 128
#define HID 256
#define HEADS 8
#define DH 32
#define LAYERS 3
#define NUM_GRAPHS 64
#define OUT_DIM 10
#define SLOPE 0.2f

// src-bucketed CSR: bucket = src >> 12 (4096 nodes = 2 MB of fsb per bucket)
#define NBKT 5
#define N_BINS (N_NODES * NBKT)
#define SCAN_BLK 1024
#define SCAN_NBLK ((N_BINS + SCAN_BLK - 1) / SCAN_BLK)   // 98

typedef __bf16 bf16x8 __attribute__((ext_vector_type(8)));
typedef float f32x4 __attribute__((ext_vector_type(4)));

static __device__ __forceinline__ unsigned short f2bfbits(float v) {
    __bf16 b = (__bf16)v;
    return __builtin_bit_cast(unsigned short, b);
}
// unpack 8 bf16 (in a uint4) -> 8 fp32, exact
static __device__ __forceinline__ void unpack8(uint4 u, float* f) {
    unsigned p0 = u.x, p1 = u.y, p2 = u.z, p3 = u.w;
    f[0] = __builtin_bit_cast(float, p0 << 16);
    f[1] = __builtin_bit_cast(float, p0 & 0xffff0000u);
    f[2] = __builtin_bit_cast(float, p1 << 16);
    f[3] = __builtin_bit_cast(float, p1 & 0xffff0000u);
    f[4] = __builtin_bit_cast(float, p2 << 16);
    f[5] = __builtin_bit_cast(float, p2 & 0xffff0000u);
    f[6] = __builtin_bit_cast(float, p3 << 16);
    f[7] = __builtin_bit_cast(float, p3 & 0xffff0000u);
}
// unpack 4 bf16 (in a uint2) -> 4 fp32, exact
static __device__ __forceinline__ void unpack4(uint2 u, float* f) {
    f[0] = __builtin_bit_cast(float, u.x << 16);
    f[1] = __builtin_bit_cast(float, u.x & 0xffff0000u);
    f[2] = __builtin_bit_cast(float, u.y << 16);
    f[3] = __builtin_bit_cast(float, u.y & 0xffff0000u);
}

// async 16B global->LDS (DMA, wave-uniform LDS base + lane*16)
typedef const __attribute__((address_space(1))) unsigned int* as1_u32p;
typedef __attribute__((address_space(3))) unsigned int* as3_u32p;
static __device__ __forceinline__ void async_cp16(const unsigned short* g, unsigned short* l) {
    __builtin_amdgcn_global_load_lds((as1_u32p)g, (as3_u32p)l, 16, 0, 0);
}

// ---------------- fused prep: zero cnt+hg, feature cast, weight transpose/cast ----------------
#define CAST_N4 (N_NODES * IN_DIM / 4)
#define WTRANS_TOTAL (IN_DIM * HID + 6 * HID * HID)
#define ZERO_TOTAL (N_BINS + NUM_GRAPHS * HID)
#define PREP_TOTAL (CAST_N4 + WTRANS_TOTAL + ZERO_TOTAL)
__global__ void prep_kernel(const float* __restrict__ feat,
                            const float* __restrict__ Win,
                            const float* __restrict__ Wsrc,
                            const float* __restrict__ Wdst,
                            unsigned short* __restrict__ featH,
                            unsigned short* __restrict__ WinT,
                            unsigned short* __restrict__ WT,
                            int* __restrict__ cnt, float* __restrict__ hg) {
    int idx = blockIdx.x * blockDim.x + threadIdx.x;
    if (idx < CAST_N4) {
        float4 v = ((const float4*)feat)[idx];
        ushort4 o;
        o.x = f2bfbits(v.x); o.y = f2bfbits(v.y);
        o.z = f2bfbits(v.z); o.w = f2bfbits(v.w);
        ((ushort4*)featH)[idx] = o;
    } else if (idx < CAST_N4 + WTRANS_TOTAL) {
        int j = idx - CAST_N4;
        if (j < IN_DIM * HID) {
            int n = j / IN_DIM, k = j % IN_DIM;
            WinT[j] = f2bfbits(Win[k * HID + n]);
        } else {
            int r6 = j - IN_DIM * HID;
            int mat = r6 >> 16;
            int r = r6 & 65535;
            int n = r >> 8, k = r & 255;
            const float* base = (mat < 3) ? (Wsrc + (size_t)mat * 65536)
                                          : (Wdst + (size_t)(mat - 3) * 65536);
            WT[r6] = f2bfbits(base[k * 256 + n]);
        }
    } else if (idx < PREP_TOTAL) {
        int z = idx - CAST_N4 - WTRANS_TOTAL;
        if (z < N_BINS) cnt[z] = 0;
        else hg[z - N_BINS] = 0.f;
    }
}

// ---------------- CSR build, keyed by (dst, src-bucket) ----------------
__global__ void count_kernel(const int* __restrict__ src, const int* __restrict__ dst,
                             int* __restrict__ cnt) {
    int e = blockIdx.x * blockDim.x + threadIdx.x;
    if (e < N_EDGES) atomicAdd(&cnt[dst[e] * NBKT + (src[e] >> 12)], 1);
}

// hierarchical scan, stage 1: per-block (1024 bins) sums, coalesced
__global__ __launch_bounds__(1024) void scan_partial(const int* __restrict__ cnt,
                                                     int* __restrict__ bsum) {
    __shared__ int wsum[16];
    int t = threadIdx.x;
    int idx = blockIdx.x * SCAN_BLK + t;
    int x = (idx < N_BINS) ? cnt[idx] : 0;
    int v = x;
#pragma unroll
    for (int d = 1; d < 64; d <<= 1) v += __shfl_xor(v, d, 64);
    if ((t & 63) == 0) wsum[t >> 6] = v;
    __syncthreads();
    if (t == 0) {
        int s = 0;
#pragma unroll
        for (int i = 0; i < 16; ++i) s += wsum[i];
        bsum[blockIdx.x] = s;
    }
}

// hierarchical scan, stage 2: block base from bsum prefix + block-wide
// exclusive scan of its 1024 bins (coalesced), writes offs & cursor.
__global__ __launch_bounds__(1024) void scan_scatter(const int* __restrict__ cnt,
                                                     const int* __restrict__ bsum,
                                                     int* __restrict__ offs,
                                                     int* __restrict__ cursor) {
    __shared__ int wsum[16];
    __shared__ int bpart[128];
    __shared__ int sbase;
    int t = threadIdx.x;
    int blk = blockIdx.x;
    if (t < 128) bpart[t] = (t < blk) ? bsum[t] : 0;   // blk <= 97 < 128
    __syncthreads();
    if (t < 64) {
        int r = bpart[t] + bpart[t + 64];
#pragma unroll
        for (int d = 1; d < 64; d <<= 1) r += __shfl_xor(r, d, 64);
        if (t == 0) sbase = r;
    }
    int idx = blk * SCAN_BLK + t;
    int x = (idx < N_BINS) ? cnt[idx] : 0;
    int v = x;
#pragma unroll
    for (int d = 1; d < 64; d <<= 1) {
        int u = __shfl_up(v, d, 64);
        if ((t & 63) >= d) v += u;
    }
    if ((t & 63) == 63) wsum[t >> 6] = v;
    __syncthreads();
    if (t < 16) {
        int wv = wsum[t];
#pragma unroll
        for (int d = 1; d < 16; d <<= 1) {
            int u = __shfl_up(wv, d, 64);
            if (t >= d) wv += u;
        }
        wsum[t] = wv;
    }
    __syncthreads();
    int waveoff = (t >> 6) ? wsum[(t >> 6) - 1] : 0;
    int ex = sbase + waveoff + v - x;   // global exclusive prefix for bin idx
    if (idx < N_BINS) { offs[idx] = ex; cursor[idx] = ex; }
    if (blk == SCAN_NBLK - 1 && t == SCAN_BLK - 1) offs[N_BINS] = ex + x;
}

__global__ void fill_kernel(const int* __restrict__ src, const int* __restrict__ dst,
                            int* __restrict__ cursor, int* __restrict__ csr_src) {
    int e = blockIdx.x * blockDim.x + threadIdx.x;
    if (e < N_EDGES) {
        int sv = src[e];
        int p = atomicAdd(&cursor[dst[e] * NBKT + (sv >> 12)], 1);
        csr_src[p] = sv;
    }
}

// ---------------- MFMA GEMM (round-17 structure): bf16 A, M64 x N128, BK=32 ----------------
template <int DUAL>
__global__ __launch_bounds__(256, 4) void mfma_gemm(
    const unsigned short* __restrict__ Ah,
    const unsigned short* __restrict__ BT1, const float* __restrict__ bias1,
    unsigned short* __restrict__ O1,
    const unsigned short* __restrict__ BT2, const float* __restrict__ bias2,
    unsigned short* __restrict__ O2,
    int M, int K, int N) {
    __shared__ __align__(16) unsigned short As[2][64 * 32];
    __shared__ __align__(16) unsigned short Bs1[2][128 * 32];
    __shared__ __align__(16) unsigned short Bs2[DUAL ? 2 : 1][DUAL ? 128 * 32 : 8];

    const int t = threadIdx.x;
    const int wv = t >> 6, lane = t & 63, quad = lane >> 4, l15 = lane & 15;
    const int m0 = blockIdx.x * 64, n0 = blockIdx.y * 128;

    const int sA = wv * 64 + lane;
    const int rA = sA >> 2, cA = (sA & 3) ^ ((rA >> 1) & 3);
    int gmA = m0 + rA; if (gmA >= M) gmA = M - 1;
    const size_t offA = (size_t)gmA * K + cA * 8;
    const int sB0 = wv * 64 + lane, sB1v = sB0 + 256;
    const int rB0 = sB0 >> 2, cB0 = (sB0 & 3) ^ ((rB0 >> 1) & 3);
    const int rB1 = sB1v >> 2, cB1 = (sB1v & 3) ^ ((rB1 >> 1) & 3);
    const size_t offB0 = (size_t)(n0 + rB0) * K + cB0 * 8;
    const size_t offB1 = (size_t)(n0 + rB1) * K + cB1 * 8;

    auto issue = [&](int buf, int k0) {
        async_cp16(Ah + offA + k0, &As[buf][wv * 512]);
        async_cp16(BT1 + offB0 + k0, &Bs1[buf][wv * 512]);
        async_cp16(BT1 + offB1 + k0, &Bs1[buf][2048 + wv * 512]);
        if (DUAL) {
            async_cp16(BT2 + offB0 + k0, &Bs2[buf][wv * 512]);
            async_cp16(BT2 + offB1 + k0, &Bs2[buf][2048 + wv * 512]);
        }
    };

    const int mrow0 = (wv >> 1) * 32;
    const int ncb = (wv & 1) * 64;

    f32x4 zero = {0.f, 0.f, 0.f, 0.f};
    f32x4 acc1[2][4], acc2[2][4];
#pragma unroll
    for (int mi = 0; mi < 2; ++mi)
#pragma unroll
        for (int t4 = 0; t4 < 4; ++t4) { acc1[mi][t4] = zero; acc2[mi][t4] = zero; }

    issue(0, 0);
    int buf = 0;
    for (int k0 = 0; k0 < K; k0 += 32, buf ^= 1) {
        __syncthreads();
        if (k0 + 32 < K) issue(buf ^ 1, k0 + 32);

        bf16x8 aF[2];
#pragma unroll
        for (int mi = 0; mi < 2; ++mi) {
            int row = mrow0 + mi * 16 + l15;
            int aoff = row * 32 + ((quad ^ ((row >> 1) & 3)) << 3);
            aF[mi] = __builtin_bit_cast(bf16x8, *(const uint4*)(&As[buf][0] + aoff));
        }
#pragma unroll
        for (int t4 = 0; t4 < 4; ++t4) {
            int brow = ncb + t4 * 16 + l15;
            int boff = brow * 32 + ((quad ^ ((brow >> 1) & 3)) << 3);
            bf16x8 b1 = __builtin_bit_cast(bf16x8, *(const uint4*)(&Bs1[buf][0] + boff));
#pragma unroll
            for (int mi = 0; mi < 2; ++mi)
                acc1[mi][t4] = __builtin_amdgcn_mfma_f32_16x16x32_bf16(aF[mi], b1, acc1[mi][t4], 0, 0, 0);
            if (DUAL) {
                bf16x8 b2 = __builtin_bit_cast(bf16x8, *(const uint4*)(&Bs2[buf][0] + boff));
#pragma unroll
                for (int mi = 0; mi < 2; ++mi)
                    acc2[mi][t4] = __builtin_amdgcn_mfma_f32_16x16x32_bf16(aF[mi], b2, acc2[mi][t4], 0, 0, 0);
            }
        }
    }

    float bia1[4], bia2[4];
#pragma unroll
    for (int t4 = 0; t4 < 4; ++t4) {
        bia1[t4] = bias1[n0 + ncb + t4 * 16 + l15];
        bia2[t4] = DUAL ? bias2[n0 + ncb + t4 * 16 + l15] : 0.f;
    }
#pragma unroll
    for (int mi = 0; mi < 2; ++mi) {
#pragma unroll
        for (int t4 = 0; t4 < 4; ++t4) {
            int gn = n0 + ncb + t4 * 16 + l15;
#pragma unroll
            for (int r = 0; r < 4; ++r) {
                int gm = m0 + mrow0 + mi * 16 + quad * 4 + r;
                if (gm < M) {
                    float v = acc1[mi][t4][r] + bia1[t4];
                    O1[(size_t)gm * N + gn] = f2bfbits(v);
                    if (DUAL) {
                        float v2 = acc2[mi][t4][r] + bia2[t4];
                        O2[(size_t)gm * N + gn] = f2bfbits(v2);
                    }
                }
            }
        }
    }
}

// ---------------- GATv2 aggregation v4, bf16-unified h, bucket-sorted edges ----------------
__global__ __launch_bounds__(256) void gat_agg2(
    const unsigned short* __restrict__ fsb, const unsigned short* __restrict__ fdb,
    unsigned short* __restrict__ hb, const int* __restrict__ offs,
    const int* __restrict__ csr_src, const float* __restrict__ attn_l) {
    int tid = threadIdx.x;
    int node = (blockIdx.x * blockDim.x + tid) >> 5;
    if (node >= N_NODES) return;
    int l32 = tid & 31;
    int dbase = l32 * 8;
    int abase = (l32 >> 2) * DH + (l32 & 3) * 8;

    float a[8];
#pragma unroll
    for (int j = 0; j < 8; ++j) a[j] = attn_l[abase + j];

    float fdv[8];
    unpack8(*(const uint4*)(fdb + (size_t)node * HID + dbase), fdv);

    float ssum0 = 0.f, ssum1 = 0.f;
    float acc0[8], acc1[8];
#pragma unroll
    for (int j = 0; j < 8; ++j) { acc0[j] = 0.f; acc1[j] = 0.f; }

    auto procE = [&](uint4 u, float* acc, float& ssum) {
        float fsv[8];
        unpack8(u, fsv);
        float p = 0.f;
#pragma unroll
        for (int j = 0; j < 8; ++j) {
            float e = fsv[j] + fdv[j];
            e = fmaxf(e, SLOPE * e);   // leakyrelu (slope<1)
            p += e * a[j];
        }
        p += __shfl_xor(p, 1, 64);
        p += __shfl_xor(p, 2, 64);
        float w = __expf(p);
        ssum += w;
#pragma unroll
        for (int j = 0; j < 8; ++j) acc[j] += w * fsv[j];
    };

    const unsigned short* fsl = fsb + dbase;
    int beg = offs[node * NBKT], end = offs[node * NBKT + NBKT];
    int nfull = (end - beg) >> 2;
    const int limit = beg + nfull * 4;

    uint4 cu0, cu1, cu2, cu3;
    int ci0, ci1, ci2, ci3;
    int base = beg + 8;
    bool have = (nfull >= 1);
    bool haveN = (nfull >= 2);
    if (have) {
        int s0 = csr_src[beg], s1 = csr_src[beg + 1];
        int s2 = csr_src[beg + 2], s3 = csr_src[beg + 3];
        if (haveN) {
            ci0 = csr_src[beg + 4]; ci1 = csr_src[beg + 5];
            ci2 = csr_src[beg + 6]; ci3 = csr_src[beg + 7];
        }
        cu0 = *(const uint4*)(fsl + (size_t)s0 * HID);
        cu1 = *(const uint4*)(fsl + (size_t)s1 * HID);
        cu2 = *(const uint4*)(fsl + (size_t)s2 * HID);
        cu3 = *(const uint4*)(fsl + (size_t)s3 * HID);
    }
    while (have) {
        uint4 nu0, nu1, nu2, nu3;
        int ni0, ni1, ni2, ni3;
        if (haveN) {
            nu0 = *(const uint4*)(fsl + (size_t)ci0 * HID);
            nu1 = *(const uint4*)(fsl + (size_t)ci1 * HID);
            nu2 = *(const uint4*)(fsl + (size_t)ci2 * HID);
            nu3 = *(const uint4*)(fsl + (size_t)ci3 * HID);
        }
        bool haveNN = (base + 4 <= limit);
        if (haveNN) {
            ni0 = csr_src[base]; ni1 = csr_src[base + 1];
            ni2 = csr_src[base + 2]; ni3 = csr_src[base + 3];
        }
        base += 4;
        procE(cu0, acc0, ssum0);
        procE(cu1, acc1, ssum1);
        procE(cu2, acc0, ssum0);
        procE(cu3, acc1, ssum1);
        if (haveN) { cu0 = nu0; cu1 = nu1; cu2 = nu2; cu3 = nu3; }
        if (haveNN) { ci0 = ni0; ci1 = ni1; ci2 = ni2; ci3 = ni3; }
        have = haveN; haveN = haveNN;
    }
    for (int idx = limit; idx < end; ++idx) {
        int sv = csr_src[idx];
        procE(*(const uint4*)(fsl + (size_t)sv * HID), acc0, ssum0);
    }

    float ssum = ssum0 + ssum1;
    float acc[8];
#pragma unroll
    for (int j = 0; j < 8; ++j) acc[j] = acc0[j] + acc1[j];

    float inv = ssum > 0.f ? 1.f / ssum : 0.f;
    float hv[8];
    unpack8(*(const uint4*)(hb + (size_t)node * HID + dbase), hv);
    unsigned short ob[8];
#pragma unroll
    for (int j = 0; j < 8; ++j) {
        float o = fmaxf(acc[j] * inv + hv[j], 0.f);
        ob[j] = f2bfbits(o);
    }
    *(uint4*)(hb + (size_t)node * HID + dbase) = *(uint4*)ob;
}

// ---------------- graph sum-pool (bf16 h; graph_ids sorted) ----------------
#define POOL_CHUNK 32
__global__ __launch_bounds__(64) void pool_kernel(const unsigned short* __restrict__ hb,
                                                  const int* __restrict__ gid,
                                                  float* __restrict__ hg) {
    int t = threadIdx.x;
    int n0 = blockIdx.x * POOL_CHUNK;
    int n1 = n0 + POOL_CHUNK; if (n1 > N_NODES) n1 = N_NODES;
    if (n0 >= N_NODES) return;
    float acc[4] = {0.f, 0.f, 0.f, 0.f};
    int cur = gid[n0];
    for (int n = n0; n < n1; ++n) {
        int g = gid[n];
        if (g != cur) {
            atomicAdd(&hg[(size_t)cur * HID + t * 4 + 0], acc[0]);
            atomicAdd(&hg[(size_t)cur * HID + t * 4 + 1], acc[1]);
            atomicAdd(&hg[(size_t)cur * HID + t * 4 + 2], acc[2]);
            atomicAdd(&hg[(size_t)cur * HID + t * 4 + 3], acc[3]);
            acc[0] = acc[1] = acc[2] = acc[3] = 0.f;
            cur = g;
        }
        float v[4];
        unpack4(*(const uint2*)(hb + (size_t)n * HID + t * 4), v);
        acc[0] += v[0]; acc[1] += v[1]; acc[2] += v[2]; acc[3] += v[3];
    }
    atomicAdd(&hg[(size_t)cur * HID + t * 4 + 0], acc[0]);
    atomicAdd(&hg[(size_t)cur * HID + t * 4 + 1], acc[1]);
    atomicAdd(&hg[(size_t)cur * HID + t * 4 + 2], acc[2]);
    atomicAdd(&hg[(size_t)cur * HID + t * 4 + 3], acc[3]);
}

// ---------------- classifier: one block per graph ----------------
__global__ __launch_bounds__(256) void classifier_kernel(
    const float* __restrict__ hg,
    const float* __restrict__ Wc1, const float* __restrict__ bc1,
    const float* __restrict__ Wc2, const float* __restrict__ bc2,
    const float* __restrict__ Wc3, const float* __restrict__ bc3,
    float* __restrict__ out) {
    __shared__ float xin[HID];
    __shared__ float x1[HID];
    __shared__ float x2[HID / 2];
    int g = blockIdx.x, t = threadIdx.x;
    xin[t] = hg[(size_t)g * HID + t];
    __syncthreads();
    {
        float acc = bc1[t];
        for (int k = 0; k < HID; ++k) acc += xin[k] * Wc1[k * HID + t];
        x1[t] = fmaxf(acc, 0.f);
    }
    __syncthreads();
    if (t < HID / 2) {
        float acc = bc2[t];
        for (int k = 0; k < HID; ++k) acc += x1[k] * Wc2[k * (HID / 2) + t];
        x2[t] = fmaxf(acc, 0.f);
    }
    __syncthreads();
    if (t < OUT_DIM) {
        float acc = bc3[t];
        for (int k = 0; k < HID / 2; ++k) acc += x2[k] * Wc3[k * OUT_DIM + t];
        out[g * OUT_DIM + t] = acc;
    }
}

// ---------------- launch ----------------
extern "C" void kernel_launch(void* const* d_in, const int* in_sizes, int n_in,
                              void* d_out, int out_size, void* d_ws, size_t ws_size,
                              hipStream_t stream) {
    const float* feature = (const float*)d_in[0];
    const float* W_in   = (const float*)d_in[1];
    const float* b_in   = (const float*)d_in[2];
    const float* W_src  = (const float*)d_in[3];
    const float* b_src  = (const float*)d_in[4];
    const float* W_dst  = (const float*)d_in[5];
    const float* b_dst  = (const float*)d_in[6];
    const float* attn   = (const float*)d_in[7];
    const float* Wc1    = (const float*)d_in[8];
    const float* bc1    = (const float*)d_in[9];
    const float* Wc2    = (const float*)d_in[10];
    const float* bc2    = (const float*)d_in[11];
    const float* Wc3    = (const float*)d_in[12];
    const float* bc3    = (const float*)d_in[13];
    const int* src     = (const int*)d_in[14];
    const int* dst     = (const int*)d_in[15];
    const int* gid     = (const int*)d_in[16];
    float* out = (float*)d_out;

    char* w = (char*)d_ws;
    auto alloc = [&](size_t bytes) -> void* {
        void* p = (void*)w;
        w += (bytes + 255) & ~(size_t)255;
        return p;
    };
    unsigned short* hb  = (unsigned short*)alloc((size_t)N_NODES * HID * 2);  // unified bf16 h
    unsigned short* fsb = (unsigned short*)alloc((size_t)N_NODES * HID * 2);
    unsigned short* fdb = (unsigned short*)alloc((size_t)N_NODES * HID * 2);
    float* hg    = (float*)alloc((size_t)NUM_GRAPHS * HID * 4);
    int* cnt     = (int*)alloc((size_t)N_BINS * 4);
    int* offs    = (int*)alloc((size_t)(N_BINS + 1) * 4);
    int* cursor  = (int*)alloc((size_t)N_BINS * 4);
    int* csr_src = (int*)alloc((size_t)N_EDGES * 4);
    int* bsum    = (int*)alloc((size_t)SCAN_NBLK * 4);
    unsigned short* WinT = (unsigned short*)alloc((size_t)IN_DIM * HID * 2);
    unsigned short* WT   = (unsigned short*)alloc((size_t)6 * HID * HID * 2);
    unsigned short* featH = (unsigned short*)alloc((size_t)N_NODES * IN_DIM * 2);
    (void)alloc(4096);  // slack for clamped staging overreach

    // prep: zero cnt+hg, feature cast, weight transposes (one dispatch)
    hipLaunchKernelGGL(prep_kernel, dim3((PREP_TOTAL + 255) / 256), dim3(256), 0, stream,
                       feature, W_in, W_src, W_dst, featH, WinT, WT, cnt, hg);

    // CSR build keyed by (dst, src-bucket); hierarchical scan over 100k bins
    hipLaunchKernelGGL(count_kernel, dim3((N_EDGES + 255) / 256), dim3(256), 0, stream,
                       src, dst, cnt);
    hipLaunchKernelGGL(scan_partial, dim3(SCAN_NBLK), dim3(SCAN_BLK), 0, stream, cnt, bsum);
    hipLaunchKernelGGL(scan_scatter, dim3(SCAN_NBLK), dim3(SCAN_BLK), 0, stream,
                       cnt, bsum, offs, cursor);
    hipLaunchKernelGGL(fill_kernel, dim3((N_EDGES + 255) / 256), dim3(256), 0, stream,
                       src, dst, cursor, csr_src);

    dim3 ggrid((N_NODES + 63) / 64, HID / 128);  // 313 x 2

    // input projection: hb = bf16(feature @ W_in + b_in)
    hipLaunchKernelGGL((mfma_gemm<0>), ggrid, dim3(256), 0, stream,
                       featH, WinT, b_in, hb,
                       (const unsigned short*)nullptr, (const float*)nullptr,
                       (unsigned short*)nullptr,
                       N_NODES, IN_DIM, HID);

    // GATv2 layers
    for (int l = 0; l < LAYERS; ++l) {
        hipLaunchKernelGGL((mfma_gemm<1>), ggrid, dim3(256), 0, stream,
                           hb,
                           WT + (size_t)l * HID * HID, b_src + (size_t)l * HID, fsb,
                           WT + (size_t)(3 + l) * HID * HID, b_dst + (size_t)l * HID, fdb,
                           N_NODES, HID, HID);
        hipLaunchKernelGGL(gat_agg2, dim3(N_NODES / 8), dim3(256), 0, stream,
                           fsb, fdb, hb, offs, csr_src, attn + (size_t)l * HEADS * DH);
    }

    // pool + classifier
    hipLaunchKernelGGL(pool_kernel, dim3((N_NODES + POOL_CHUNK - 1) / POOL_CHUNK), dim3(64), 0, stream,
                       hb, gid, hg);
    hipLaunchKernelGGL(classifier_kernel, dim3(NUM_GRAPHS), dim3(256), 0, stream,
                       hg, Wc1, bc1, Wc2, bc2, Wc3, bc3, out);
}